// Round 2
// baseline (617.242 us; speedup 1.0000x reference)
//
#include <hip/hip_runtime.h>

#define B 32
#define LQ 32
#define DLEN 4096
#define P 16
#define D 2048
#define H 2048
#define HCHUNK 64

// ---------------------------------------------------------------------------
// Kernel 0: zero v (B*D floats). Replaces hipMemsetAsync for capture safety.
// ---------------------------------------------------------------------------
__global__ __launch_bounds__(256) void zero_v_kernel(float* __restrict__ v) {
  const int i = blockIdx.x * 256 + threadIdx.x;
  if (i < B * D) v[i] = 0.f;
}

// ---------------------------------------------------------------------------
// Kernel 1: gather + masked mean.
// Blocks [0, B*P): passage (b,p) -> p_rep[b*P+p][:]
// Blocks [B*P, B*P+B): query b   -> q_rep[b][:]
// 512 threads, each owns 4 contiguous columns (float4) of D=2048.
// Token ids staged in LDS; unroll-4 token loop for outstanding loads.
// ---------------------------------------------------------------------------
__global__ __launch_bounds__(512) void gather_mean_kernel(
    const int* __restrict__ queries, const int* __restrict__ qlen,
    const int* __restrict__ docs, const int* __restrict__ plen,
    const float* __restrict__ emb,
    float* __restrict__ q_rep, float* __restrict__ p_rep)
{
  __shared__ int stok[256];
  const int bid = blockIdx.x;
  const int* toks;
  int len;
  float* outp;

  if (bid < B * P) {
    const int b = bid >> 4;
    const int p = bid & 15;
    int s = 0;
#pragma unroll
    for (int i = 0; i < P; ++i) s += (i < p) ? plen[b * P + i] : 0;
    len  = plen[b * P + p];
    toks = docs + b * DLEN + s;
    outp = p_rep + (size_t)bid * D;
  } else {
    const int b = bid - B * P;
    len  = qlen[b];
    toks = queries + b * LQ;
    outp = q_rep + (size_t)b * D;
  }

  for (int i = threadIdx.x; i < len; i += blockDim.x) stok[i] = toks[i];
  __syncthreads();

  const int tid = threadIdx.x;
  float4 acc = make_float4(0.f, 0.f, 0.f, 0.f);

  int t = 0;
  for (; t + 4 <= len; t += 4) {
    const float4* r0 = (const float4*)(emb + (size_t)stok[t + 0] * D);
    const float4* r1 = (const float4*)(emb + (size_t)stok[t + 1] * D);
    const float4* r2 = (const float4*)(emb + (size_t)stok[t + 2] * D);
    const float4* r3 = (const float4*)(emb + (size_t)stok[t + 3] * D);
    const float4 a0 = r0[tid];
    const float4 a1 = r1[tid];
    const float4 a2 = r2[tid];
    const float4 a3 = r3[tid];
    acc.x += (a0.x + a1.x) + (a2.x + a3.x);
    acc.y += (a0.y + a1.y) + (a2.y + a3.y);
    acc.z += (a0.z + a1.z) + (a2.z + a3.z);
    acc.w += (a0.w + a1.w) + (a2.w + a3.w);
  }
  for (; t < len; ++t) {
    const float4* r = (const float4*)(emb + (size_t)stok[t] * D);
    const float4 a = r[tid];
    acc.x += a.x; acc.y += a.y; acc.z += a.z; acc.w += a.w;
  }

  const float inv = 1.0f / (float)(len > 0 ? len : 1);
  ((float4*)outp)[tid] =
      make_float4(acc.x * inv, acc.y * inv, acc.z * inv, acc.w * inv);
}

// ---------------------------------------------------------------------------
// Kernel 2: q_enc[b][h] = dot(q_rep[b], W[h]) + bias[h]
// grid = H blocks (one W-row each, staged in LDS), 256 threads = 4 waves.
// Each wave owns batch rows b = wid, wid+4, ... -> wave-synchronous
// shuffle reduction, no inner __syncthreads.
// ---------------------------------------------------------------------------
__global__ __launch_bounds__(256) void qenc_kernel(
    const float* __restrict__ q_rep, const float* __restrict__ W,
    const float* __restrict__ bias, float* __restrict__ q_enc)
{
  const int h = blockIdx.x;
  __shared__ float wsh[D];
  for (int c = threadIdx.x; c < D; c += 256)
    wsh[c] = W[(size_t)h * D + c];
  __syncthreads();

  const float bh   = bias[h];
  const int   lane = threadIdx.x & 63;
  const int   wid  = threadIdx.x >> 6;

  for (int b = wid; b < B; b += 4) {
    float s = 0.f;
#pragma unroll
    for (int k = 0; k < D / 64; ++k) {
      const int c = k * 64 + lane;
      s += wsh[c] * q_rep[b * D + c];
    }
#pragma unroll
    for (int off = 32; off; off >>= 1) s += __shfl_down(s, off, 64);
    if (lane == 0) q_enc[b * H + h] = s + bh;
  }
}

// ---------------------------------------------------------------------------
// Kernel 3: v[b][d] = sum_h q_enc[b][h] * W[h][d]   (v = W^T q_enc)
// grid = (D/256, H/HCHUNK); partials accumulated with coalesced atomics.
// v zeroed by zero_v_kernel beforehand.
// ---------------------------------------------------------------------------
__global__ __launch_bounds__(256) void v_kernel(
    const float* __restrict__ q_enc, const float* __restrict__ W,
    float* __restrict__ v)
{
  const int d  = blockIdx.x * 256 + threadIdx.x;
  const int h0 = blockIdx.y * HCHUNK;

  __shared__ float qe[HCHUNK * B];  // [hh][b]
  for (int i = threadIdx.x; i < HCHUNK * B; i += 256) {
    const int hh = i >> 5;
    const int b  = i & 31;
    qe[i] = q_enc[b * H + h0 + hh];
  }
  __syncthreads();

  float acc[B];
#pragma unroll
  for (int b = 0; b < B; ++b) acc[b] = 0.f;

  for (int hh = 0; hh < HCHUNK; ++hh) {
    const float w = W[(size_t)(h0 + hh) * D + d];
#pragma unroll
    for (int b = 0; b < B; ++b) acc[b] += w * qe[hh * B + b];
  }

#pragma unroll
  for (int b = 0; b < B; ++b) atomicAdd(&v[b * D + d], acc[b]);
}

// ---------------------------------------------------------------------------
// Kernel 4: scores[b,p] = dot(v[b], p_rep[b,p]) + dot(q_enc[b], bias),
//           masked by passage_lengths > 0.
// grid = B*P blocks, 256 threads.
// ---------------------------------------------------------------------------
__global__ __launch_bounds__(256) void score_kernel(
    const float* __restrict__ v, const float* __restrict__ q_enc,
    const float* __restrict__ bias, const float* __restrict__ p_rep,
    const int* __restrict__ plen, float* __restrict__ out)
{
  const int bp = blockIdx.x;
  const int b  = bp >> 4;

  float s = 0.f;
#pragma unroll
  for (int k = 0; k < D / 256; ++k) {
    const int c = k * 256 + threadIdx.x;
    s += v[b * D + c] * p_rep[(size_t)bp * D + c];
    s += q_enc[b * H + c] * bias[c];
  }
#pragma unroll
  for (int off = 32; off; off >>= 1) s += __shfl_down(s, off, 64);

  __shared__ float red[4];
  const int lane = threadIdx.x & 63;
  const int wid  = threadIdx.x >> 6;
  if (lane == 0) red[wid] = s;
  __syncthreads();
  if (threadIdx.x == 0) {
    const float tot = red[0] + red[1] + red[2] + red[3];
    out[bp] = (plen[bp] > 0) ? tot : 0.f;
  }
}

// ---------------------------------------------------------------------------
extern "C" void kernel_launch(void* const* d_in, const int* in_sizes, int n_in,
                              void* d_out, int out_size, void* d_ws, size_t ws_size,
                              hipStream_t stream) {
  const int*   queries = (const int*)d_in[0];
  const int*   qlen    = (const int*)d_in[1];
  const int*   docs    = (const int*)d_in[2];
  const int*   plen    = (const int*)d_in[3];
  const float* emb     = (const float*)d_in[4];
  const float* W       = (const float*)d_in[5];
  const float* bias    = (const float*)d_in[6];
  float*       out     = (float*)d_out;

  float* q_rep = (float*)d_ws;                    // B*D
  float* p_rep = q_rep + B * D;                   // B*P*D
  float* q_enc = p_rep + (size_t)B * P * D;       // B*H
  float* v     = q_enc + B * H;                   // B*D

  zero_v_kernel<<<(B * D + 255) / 256, 256, 0, stream>>>(v);
  gather_mean_kernel<<<B * P + B, 512, 0, stream>>>(queries, qlen, docs, plen,
                                                    emb, q_rep, p_rep);
  qenc_kernel<<<H, 256, 0, stream>>>(q_rep, W, bias, q_enc);
  dim3 vgrid(D / 256, H / HCHUNK);
  v_kernel<<<vgrid, 256, 0, stream>>>(q_enc, W, v);
  score_kernel<<<B * P, 256, 0, stream>>>(v, q_enc, bias, p_rep, plen, out);
}

// Round 3
// 609.582 us; speedup vs baseline: 1.0126x; 1.0126x over previous
//
#include <hip/hip_runtime.h>

#define B 32
#define LQ 32
#define DLEN 4096
#define P 16
#define D 2048
#define H 2048
#define NC 32   // doc chunks per batch (grid.x of docscore)
#define HC 32   // h-rows per v_kernel block
#define HB 4    // W-rows per qenc block

// ---------------------------------------------------------------------------
// K0: zero v[B*D] and sacc[B*P]
// ---------------------------------------------------------------------------
__global__ __launch_bounds__(256) void zero_kernel(float* __restrict__ v,
                                                   float* __restrict__ sacc) {
  const int i = blockIdx.x * 256 + threadIdx.x;
  if (i < B * D) v[i] = 0.f;
  if (i < B * P) sacc[i] = 0.f;
}

// ---------------------------------------------------------------------------
// K1: q_rep[b][:] = masked mean of query token embeddings. 32 blocks.
// Each thread owns float4 indices tid and tid+256 (D/4 = 512).
// ---------------------------------------------------------------------------
__global__ __launch_bounds__(256) void qrep_kernel(
    const int* __restrict__ queries, const int* __restrict__ qlen,
    const float* __restrict__ emb, float* __restrict__ q_rep) {
  __shared__ int stok[LQ];
  const int b   = blockIdx.x;
  const int len = qlen[b];
  if (threadIdx.x < len) stok[threadIdx.x] = queries[b * LQ + threadIdx.x];
  __syncthreads();

  float4 a0 = make_float4(0.f, 0.f, 0.f, 0.f);
  float4 a1 = make_float4(0.f, 0.f, 0.f, 0.f);
  for (int t = 0; t < len; ++t) {
    const float4* r = (const float4*)(emb + (size_t)stok[t] * D);
    const float4 x = r[threadIdx.x];
    const float4 y = r[threadIdx.x + 256];
    a0.x += x.x; a0.y += x.y; a0.z += x.z; a0.w += x.w;
    a1.x += y.x; a1.y += y.y; a1.z += y.z; a1.w += y.w;
  }
  const float inv = 1.0f / (float)len;  // len >= 4 by construction
  float4* o = (float4*)(q_rep + (size_t)b * D);
  o[threadIdx.x]       = make_float4(a0.x*inv, a0.y*inv, a0.z*inv, a0.w*inv);
  o[threadIdx.x + 256] = make_float4(a1.x*inv, a1.y*inv, a1.z*inv, a1.w*inv);
}

// ---------------------------------------------------------------------------
// K2: q_enc[b][h] = dot(q_rep[b], W[h]) + bias[h].
// grid = H/HB blocks; HB W-rows staged in LDS (float4); 4 waves own
// disjoint b's -> wave-synchronous shuffle reduce, no inner barriers.
// ---------------------------------------------------------------------------
__global__ __launch_bounds__(256) void qenc_kernel(
    const float* __restrict__ q_rep, const float* __restrict__ W,
    const float* __restrict__ bias, float* __restrict__ q_enc) {
  const int h0 = blockIdx.x * HB;
  __shared__ float4 wsh[HB][D / 4];
  for (int i = threadIdx.x; i < HB * (D / 4); i += 256) {
    const int r = i / (D / 4), c = i % (D / 4);
    wsh[r][c] = ((const float4*)(W + (size_t)(h0 + r) * D))[c];
  }
  __syncthreads();

  const int lane = threadIdx.x & 63, wid = threadIdx.x >> 6;
  for (int b = wid; b < B; b += 4) {
    const float4* q4 = (const float4*)(q_rep + (size_t)b * D);
    float s[HB] = {0.f, 0.f, 0.f, 0.f};
#pragma unroll
    for (int j = 0; j < 8; ++j) {
      const float4 q = q4[j * 64 + lane];
#pragma unroll
      for (int r = 0; r < HB; ++r) {
        const float4 w = wsh[r][j * 64 + lane];
        s[r] += w.x * q.x + w.y * q.y + w.z * q.z + w.w * q.w;
      }
    }
#pragma unroll
    for (int r = 0; r < HB; ++r) {
      float t = s[r];
#pragma unroll
      for (int off = 32; off; off >>= 1) t += __shfl_down(t, off, 64);
      if (lane == 0) q_enc[b * H + h0 + r] = t + bias[h0 + r];
    }
  }
}

// ---------------------------------------------------------------------------
// K3: v[b][d] += sum_{h in chunk} q_enc[b][h] * W[h][d].
// grid = (D/256, H/HC) = 512 blocks; coalesced W stream, unroll-4 for ILP.
// ---------------------------------------------------------------------------
__global__ __launch_bounds__(256) void v_kernel(
    const float* __restrict__ q_enc, const float* __restrict__ W,
    float* __restrict__ v) {
  const int d  = blockIdx.x * 256 + threadIdx.x;
  const int h0 = blockIdx.y * HC;

  __shared__ float qe[HC][B];
  for (int i = threadIdx.x; i < HC * B; i += 256)
    qe[i >> 5][i & 31] = q_enc[(i & 31) * H + h0 + (i >> 5)];
  __syncthreads();

  float acc[B];
#pragma unroll
  for (int b = 0; b < B; ++b) acc[b] = 0.f;

#pragma unroll 4
  for (int hh = 0; hh < HC; ++hh) {
    const float w = W[(size_t)(h0 + hh) * D + d];
#pragma unroll
    for (int b = 0; b < B; ++b) acc[b] += w * qe[hh][b];
  }
#pragma unroll
  for (int b = 0; b < B; ++b) atomicAdd(&v[b * D + d], acc[b]);
}

// ---------------------------------------------------------------------------
// K4 (dominant): per-token dots. grid = (NC, B). Block stages v[b] in LDS,
// splits batch-b's valid tokens into NC balanced chunks; each wave owns
// whole tokens (8 independent float4 loads/lane), shuffle-reduces the dot,
// accumulates into per-wave LDS bins (wave-synchronous), 16 atomics/block.
// ---------------------------------------------------------------------------
__global__ __launch_bounds__(256) void docscore_kernel(
    const int* __restrict__ docs, const int* __restrict__ plen,
    const float* __restrict__ emb, const float* __restrict__ v,
    float* __restrict__ sacc) {
  const int b = blockIdx.y;
  __shared__ float4 vsh[D / 4];       // 8 KB
  __shared__ int    cum[P];
  __shared__ int    stok[128];
  __shared__ unsigned char sp[128];
  __shared__ float  wacc[4][P];

  vsh[threadIdx.x]       = ((const float4*)(v + (size_t)b * D))[threadIdx.x];
  vsh[threadIdx.x + 256] = ((const float4*)(v + (size_t)b * D))[threadIdx.x + 256];
  if (threadIdx.x == 0) {
    int s = 0;
#pragma unroll
    for (int i = 0; i < P; ++i) { s += plen[b * P + i]; cum[i] = s; }
  }
  if (threadIdx.x < 4 * P) wacc[threadIdx.x >> 4][threadIdx.x & 15] = 0.f;
  __syncthreads();

  const int tot = cum[P - 1];
  const int per = (tot + NC - 1) / NC;        // <= 128
  const int t0  = blockIdx.x * per;
  const int t1  = (t0 + per < tot) ? (t0 + per) : tot;
  const int cnt = t1 - t0;

  for (int i = threadIdx.x; i < cnt; i += 256) {
    const int t = t0 + i;
    stok[i] = docs[b * DLEN + t];
    int p = 0;
#pragma unroll
    for (int j = 0; j < P; ++j) p += (t >= cum[j]) ? 1 : 0;
    sp[i] = (unsigned char)p;
  }
  __syncthreads();

  const int lane = threadIdx.x & 63, wid = threadIdx.x >> 6;
  for (int i = wid; i < cnt; i += 4) {
    const float4* e4 = (const float4*)(emb + (size_t)stok[i] * D);
    float s = 0.f;
#pragma unroll
    for (int j = 0; j < 8; ++j) {
      const float4 e = e4[j * 64 + lane];
      const float4 w = vsh[j * 64 + lane];
      s += e.x * w.x + e.y * w.y + e.z * w.z + e.w * w.w;
    }
#pragma unroll
    for (int off = 32; off; off >>= 1) s += __shfl_down(s, off, 64);
    if (lane == 0) wacc[wid][sp[i]] += s;
  }
  __syncthreads();

  if (threadIdx.x < P) {
    const float r = wacc[0][threadIdx.x] + wacc[1][threadIdx.x] +
                    wacc[2][threadIdx.x] + wacc[3][threadIdx.x];
    atomicAdd(&sacc[b * P + threadIdx.x], r);
  }
}

// ---------------------------------------------------------------------------
// K5: out[b,p] = sacc[b,p]/len + dot(q_enc[b], bias), masked. 32 blocks.
// ---------------------------------------------------------------------------
__global__ __launch_bounds__(256) void final_kernel(
    const float* __restrict__ q_enc, const float* __restrict__ bias,
    const float* __restrict__ sacc, const int* __restrict__ plen,
    float* __restrict__ out) {
  const int b = blockIdx.x;
  float s = 0.f;
#pragma unroll
  for (int k = 0; k < 8; ++k) {
    const int c = k * 256 + threadIdx.x;
    s += q_enc[b * H + c] * bias[c];
  }
#pragma unroll
  for (int off = 32; off; off >>= 1) s += __shfl_down(s, off, 64);

  __shared__ float red[4];
  __shared__ float qb;
  const int lane = threadIdx.x & 63, wid = threadIdx.x >> 6;
  if (lane == 0) red[wid] = s;
  __syncthreads();
  if (threadIdx.x == 0) qb = red[0] + red[1] + red[2] + red[3];
  __syncthreads();

  if (threadIdx.x < P) {
    const int l = plen[b * P + threadIdx.x];
    const float val = sacc[b * P + threadIdx.x] / (float)(l > 0 ? l : 1) + qb;
    out[b * P + threadIdx.x] = (l > 0) ? val : 0.f;
  }
}

// ---------------------------------------------------------------------------
extern "C" void kernel_launch(void* const* d_in, const int* in_sizes, int n_in,
                              void* d_out, int out_size, void* d_ws, size_t ws_size,
                              hipStream_t stream) {
  const int*   queries = (const int*)d_in[0];
  const int*   qlen    = (const int*)d_in[1];
  const int*   docs    = (const int*)d_in[2];
  const int*   plen    = (const int*)d_in[3];
  const float* emb     = (const float*)d_in[4];
  const float* W       = (const float*)d_in[5];
  const float* bias    = (const float*)d_in[6];
  float*       out     = (float*)d_out;

  float* v     = (float*)d_ws;              // B*D
  float* sacc  = v + B * D;                 // B*P
  float* q_rep = sacc + B * P;              // B*D
  float* q_enc = q_rep + B * D;             // B*H

  zero_kernel<<<(B * D + 255) / 256, 256, 0, stream>>>(v, sacc);
  qrep_kernel<<<B, 256, 0, stream>>>(queries, qlen, emb, q_rep);
  qenc_kernel<<<H / HB, 256, 0, stream>>>(q_rep, W, bias, q_enc);
  dim3 vgrid(D / 256, H / HC);
  v_kernel<<<vgrid, 256, 0, stream>>>(q_enc, W, v);
  dim3 dgrid(NC, B);
  docscore_kernel<<<dgrid, 256, 0, stream>>>(docs, plen, emb, v, sacc);
  final_kernel<<<B, 256, 0, stream>>>(q_enc, bias, sacc, plen, out);
}